// Round 1
// 142223.804 us; speedup vs baseline: 1.0346x; 1.0346x over previous
//
#include <hip/hip_runtime.h>

#define TT 1024
#define BB 64
#define HH 512
#define DD 512
#define G4H 2048
#define NBLK 256
#define NTHR 256

// ws layout (floats)
#define WS_H0 0
#define WS_C0 32768                        // REUSED: per-block barrier flags (c0 lives in registers)
#define WS_H1 65536
#define WS_C1 98304                        // c1 mirror (for final-state epilogue)
#define WS_Z0P 131072                      // 16*64*2048 = 2097152
#define WS_Z1P (131072 + 2097152)          // 16*64*2048
#define WS_HWZ (131072 + 2*2097152)        // 8*64*512  = 262144
#define WS_BAR (WS_HWZ + 262144)           // generation word @ +0

// ======== coherent (agent-scope, fence-free) global access helpers ========
// Relaxed agent atomics compile to global_load/store with sc1 and NO
// buffer_wbl2/buffer_inv — coherent at the MALL, zero cache-maintenance cost.
__device__ __forceinline__ float ldg_cg(const float* p) {
    return __hip_atomic_load(p, __ATOMIC_RELAXED, __HIP_MEMORY_SCOPE_AGENT);
}
__device__ __forceinline__ void stg_cg(float* p, float v) {
    __hip_atomic_store(p, v, __ATOMIC_RELAXED, __HIP_MEMORY_SCOPE_AGENT);
}
__device__ __forceinline__ float4 ldg_cg4(const float* p) {
    const unsigned long long* q = (const unsigned long long*)p;
    unsigned long long a = __hip_atomic_load(q,     __ATOMIC_RELAXED, __HIP_MEMORY_SCOPE_AGENT);
    unsigned long long b = __hip_atomic_load(q + 1, __ATOMIC_RELAXED, __HIP_MEMORY_SCOPE_AGENT);
    float4 v;
    ((unsigned long long*)&v)[0] = a;
    ((unsigned long long*)&v)[1] = b;
    return v;
}
__device__ __forceinline__ void stg_cg4(float* p, float4 v) {
    unsigned long long* q = (unsigned long long*)p;
    __hip_atomic_store(q,     ((unsigned long long*)&v)[0], __ATOMIC_RELAXED, __HIP_MEMORY_SCOPE_AGENT);
    __hip_atomic_store(q + 1, ((unsigned long long*)&v)[1], __ATOMIC_RELAXED, __HIP_MEMORY_SCOPE_AGENT);
}

// ======== fence-free grid barrier: flag-array + master (no RMW contention) ========
// Old design: 256 fetch_adds serialized on ONE MALL line (~150ns each -> ~40us/barrier).
// New design: each block stores its phase into its OWN 128B-strided flag (parallel,
// no ownership ping-pong). Block 0's threads 1..255 poll one peer flag each in
// parallel, then thread 0 publishes the generation word all other blocks poll.
// Data ordering argument unchanged: __syncthreads drains vmcnt(0), so this block's
// sc1 stores are at the coherence point before its flag store; consumers' sc1 loads
// issue after observing the flag/generation bump.
__device__ __forceinline__ void grid_sync(unsigned* gen, unsigned* flags, unsigned ph, int blk)
{
    __syncthreads();
    const unsigned tgt = ph + 1u;
    const int tid = threadIdx.x;
    if (blk == 0) {
        if (tid != 0) {        // thread i polls block i's flag (blocks 1..255)
            while (__hip_atomic_load(&flags[tid * 32], __ATOMIC_RELAXED, __HIP_MEMORY_SCOPE_AGENT) < tgt)
                __builtin_amdgcn_s_sleep(1);
        }
        __syncthreads();
        if (tid == 0)
            __hip_atomic_store(gen, tgt, __ATOMIC_RELAXED, __HIP_MEMORY_SCOPE_AGENT);
    } else {
        if (tid == 0) {
            __hip_atomic_store(&flags[blk * 32], tgt, __ATOMIC_RELAXED, __HIP_MEMORY_SCOPE_AGENT);
            while (__hip_atomic_load(gen, __ATOMIC_RELAXED, __HIP_MEMORY_SCOPE_AGENT) < tgt)
                __builtin_amdgcn_s_sleep(1);
        }
        __syncthreads();
    }
}

// ---------------- init: zero h/c state + flags + barrier words --------
__global__ void ln_lstm_init_kernel(float* __restrict__ ws)
{
    const int n = 131072;                  // h0, flags(C0 region), h1, c1 regions
    for (int i = blockIdx.x * blockDim.x + threadIdx.x; i < n; i += gridDim.x * blockDim.x)
        ws[i] = 0.f;
    if (blockIdx.x == 0 && threadIdx.x < 64)
        ((unsigned*)(ws + WS_BAR))[threadIdx.x] = 0u;
}

// ---------------- GEMM tile: 128 rows x 64 K-cols x 64 batch ----------------
__device__ __forceinline__ void gemm_tile(const float* __restrict__ wlds,
                                          const float* __restrict__ inT,
                                          float* __restrict__ dst,
                                          int r0, int tid)
{
    const int rq = tid >> 3;       // 0..31
    const int bq = tid & 7;        // 0..7
    const int r0t = rq * 4;
    const int b0t = bq * 8;
    float acc[4][8];
#pragma unroll
    for (int i = 0; i < 4; ++i)
#pragma unroll
        for (int bb = 0; bb < 8; ++bb) acc[i][bb] = 0.f;

#pragma unroll 4
    for (int kk = 0; kk < 64; kk += 4) {
        float4 wv[4];
#pragma unroll
        for (int i = 0; i < 4; ++i)
            wv[i] = *(const float4*)&wlds[(r0t + i) * 68 + kk];
        float4 av[4][2];
#pragma unroll
        for (int j = 0; j < 4; ++j) {
            av[j][0] = *(const float4*)&inT[(kk + j) * 68 + b0t];
            av[j][1] = *(const float4*)&inT[(kk + j) * 68 + b0t + 4];
        }
#pragma unroll
        for (int j = 0; j < 4; ++j) {
            const float* a = (const float*)&av[j][0];
#pragma unroll
            for (int i = 0; i < 4; ++i) {
                const float w = ((const float*)&wv[i])[j];
#pragma unroll
                for (int bb = 0; bb < 8; ++bb) acc[i][bb] += w * a[bb];
            }
        }
    }
#pragma unroll
    for (int bb = 0; bb < 8; ++bb) {
        float4 v; v.x = acc[0][bb]; v.y = acc[1][bb]; v.z = acc[2][bb]; v.w = acc[3][bb];
        stg_cg4(&dst[(size_t)(b0t + bb) * G4H + r0 + r0t], v);
    }
}

// ---------------- highway tile: 32 rows x 64 K x 64 batch ----------------
__device__ __forceinline__ void hw_tile(const float* __restrict__ whws,
                                        const float* __restrict__ inT,
                                        float* __restrict__ dst,
                                        int r0hw, int tid)
{
    const int rq = tid >> 5;       // 0..7
    const int bq = tid & 31;       // 0..31
    const int r0t = rq * 4;
    const int b0t = bq * 2;
    float acc[4][2];
#pragma unroll
    for (int i = 0; i < 4; ++i) { acc[i][0] = 0.f; acc[i][1] = 0.f; }

#pragma unroll 4
    for (int kk = 0; kk < 64; kk += 4) {
        float4 wv[4];
#pragma unroll
        for (int i = 0; i < 4; ++i)
            wv[i] = *(const float4*)&whws[(r0t + i) * 68 + kk];
        float2 av[4];
#pragma unroll
        for (int j = 0; j < 4; ++j)
            av[j] = *(const float2*)&inT[(kk + j) * 68 + b0t];
#pragma unroll
        for (int j = 0; j < 4; ++j)
#pragma unroll
            for (int i = 0; i < 4; ++i) {
                const float w = ((const float*)&wv[i])[j];
                acc[i][0] += w * av[j].x;
                acc[i][1] += w * av[j].y;
            }
    }
#pragma unroll
    for (int bb = 0; bb < 2; ++bb) {
        float4 v; v.x = acc[0][bb]; v.y = acc[1][bb]; v.z = acc[2][bb]; v.w = acc[3][bb];
        stg_cg4(&dst[(size_t)(b0t + bb) * HH + r0hw + r0t], v);
    }
}

// ---------------- block-wide reduction of two scalars over 256 threads ----------------
__device__ __forceinline__ void block_reduce2(float& s1, float& s2, float* sred, int tid)
{
#pragma unroll
    for (int off = 32; off > 0; off >>= 1) {
        s1 += __shfl_down(s1, off, 64);
        s2 += __shfl_down(s2, off, 64);
    }
    __syncthreads();
    if ((tid & 63) == 0) {
        const int wv = tid >> 6;
        sred[wv] = s1; sred[4 + wv] = s2;
    }
    __syncthreads();
    s1 = sred[0] + sred[1] + sred[2] + sred[3];
    s2 = sred[4] + sred[5] + sred[6] + sred[7];
}

// ---------------- block-wide reduction of 8 scalars (all 4 gates' stats at once) -------
__device__ __forceinline__ void block_reduce8(float v[8], float* sred, int tid)
{
#pragma unroll
    for (int off = 32; off > 0; off >>= 1)
#pragma unroll
        for (int k = 0; k < 8; ++k) v[k] += __shfl_down(v[k], off, 64);
    __syncthreads();
    if ((tid & 63) == 0) {
        const int wv = tid >> 6;
#pragma unroll
        for (int k = 0; k < 8; ++k) sred[k * 4 + wv] = v[k];
    }
    __syncthreads();
#pragma unroll
    for (int k = 0; k < 8; ++k)
        v[k] = sred[k * 4 + 0] + sred[k * 4 + 1] + sred[k * 4 + 2] + sred[k * 4 + 3];
}

// ---------------- LSTM cell update for one batch row; c kept in registers ------------
// Restructured vs. prior version: (a) all 128 z-partial MALL loads issued with 4
// independent accumulators per (gate,elem) -> memory-level parallelism instead of a
// dependent latency chain; (b) ONE block_reduce8 for all 4 gates' (sum, sumsq)
// instead of 4 sequential block_reduce2 rounds (removes 6 __syncthreads + 3
// reduction latencies from the critical path).
__device__ __forceinline__ void cell_update(const float* __restrict__ zp,
                                            const float* __restrict__ bias,
                                            const float* __restrict__ lng,
                                            const float* __restrict__ lnb,
                                            float creg[2], float* __restrict__ c_ws,
                                            float* __restrict__ hb,
                                            float* sred, int tid)
{
    const size_t KSTR = (size_t)64 * G4H;
    float z[4][2];
#pragma unroll
    for (int g = 0; g < 4; ++g)
#pragma unroll
        for (int e = 0; e < 2; ++e) {
            const int r = g * 512 + tid + e * 256;
            const float* p = zp + r;
            float s0 = bias[r], s1 = 0.f, s2 = 0.f, s3 = 0.f;
#pragma unroll
            for (int ks = 0; ks < 16; ks += 4) {
                s0 += ldg_cg(p + (size_t)(ks + 0) * KSTR);
                s1 += ldg_cg(p + (size_t)(ks + 1) * KSTR);
                s2 += ldg_cg(p + (size_t)(ks + 2) * KSTR);
                s3 += ldg_cg(p + (size_t)(ks + 3) * KSTR);
            }
            z[g][e] = (s0 + s1) + (s2 + s3);
        }

    float st[8];
#pragma unroll
    for (int g = 0; g < 4; ++g) {
        st[g]     = z[g][0] + z[g][1];
        st[4 + g] = z[g][0] * z[g][0] + z[g][1] * z[g][1];
    }
    block_reduce8(st, sred, tid);

    float act[4][2];
#pragma unroll
    for (int g = 0; g < 4; ++g) {
        const float mu = st[g] * (1.f / 512.f);
        const float rs = rsqrtf(st[4 + g] * (1.f / 512.f) - mu * mu + 1e-5f);
#pragma unroll
        for (int e = 0; e < 2; ++e) {
            const int j = tid + e * 256;
            const float a = (z[g][e] - mu) * rs * lng[g * 512 + j] + lnb[g * 512 + j];
            act[g][e] = (g == 2) ? tanhf(a) : 1.f / (1.f + expf(-a));
        }
    }

    float cn[2];
#pragma unroll
    for (int e = 0; e < 2; ++e) {
        cn[e] = act[1][e] * creg[e] + act[0][e] * act[2][e];
        creg[e] = cn[e];
        if (c_ws) stg_cg(c_ws + tid + e * 256, cn[e]);
    }
    float s1 = cn[0] + cn[1];
    float s2 = cn[0] * cn[0] + cn[1] * cn[1];
    block_reduce2(s1, s2, sred, tid);
    const float mu = s1 * (1.f / 512.f);
    const float rs = rsqrtf(s2 * (1.f / 512.f) - mu * mu + 1e-5f);
#pragma unroll
    for (int e = 0; e < 2; ++e) {
        const int j = tid + e * 256;
        const float a = (cn[e] - mu) * rs * lng[4 * 512 + j] + lnb[4 * 512 + j];
        stg_cg(hb + j, act[3][e] * tanhf(a));
    }
}

__global__ __launch_bounds__(NTHR, 1)
void LayerNormLSTMStack_55508157333865_kernel(
    const float* __restrict__ x,
    const float* __restrict__ W0, const float* __restrict__ b0,
    const float* __restrict__ lng0, const float* __restrict__ lnb0,
    const float* __restrict__ W1, const float* __restrict__ b1,
    const float* __restrict__ lng1, const float* __restrict__ lnb1,
    const float* __restrict__ hwW, const float* __restrict__ hwb,
    float* __restrict__ out, float* __restrict__ ws)
{
    __shared__ float wlds[128 * 68];   // 34816 B
    __shared__ float inT[64 * 68];     // 17408 B
    __shared__ float whws[32 * 68];    //  8704 B  (persistent highway weights)
    __shared__ float sred[32];

    const int tid = threadIdx.x;
    const int blk = blockIdx.x;
    const int rg = blk >> 4;          // 0..15 row-group
    const int kb = blk & 15;          // 0..15 K-slice
    const int r0 = rg * 128;          // GEMM row base

    float* h0 = ws + WS_H0;  float* h1 = ws + WS_H1;  float* c1ws = ws + WS_C1;
    float* z0p = ws + WS_Z0P; float* z1p = ws + WS_Z1P; float* hwzp = ws + WS_HWZ;
    unsigned* gen   = (unsigned*)(ws + WS_BAR);
    unsigned* flags = (unsigned*)(ws + WS_C0);

    float creg[2] = {0.f, 0.f};       // c-state for whichever cell role this block has
    unsigned ph = 0;

    // preload highway weight tile once (blocks kb>=8 own hw K-slices)
    if (kb >= 8) {
        const int r0hw = rg * 32;
        const int r = tid >> 3, kq = tid & 7;
        const float* src = hwW + (size_t)(r0hw + r) * 512 + (kb - 8) * 64 + kq * 8;
        *(float4*)&whws[r * 68 + kq * 8]     = *(const float4*)(src);
        *(float4*)&whws[r * 68 + kq * 8 + 4] = *(const float4*)(src + 4);
    }

    for (int t = 0; t <= TT; ++t) {
        // ================= P1: gemm0(t) + hw(t-1) + cell1(t-1) =================
        const bool do_g0 = (t < TT);
        const bool do_hw = (t >= 1) && (kb >= 8);
        const bool do_c1 = (t >= 1) && (kb < 4);

        if (do_g0 || do_hw) {
            const int b = tid >> 2, kq = tid & 3;
#pragma unroll
            for (int i = 0; i < 4; ++i) {
                const int kk = kq * 16 + i * 4;
                const float4 v = (kb < 8)
                    ? *(const float4*)(x + ((size_t)b * TT + t) * DD + kb * 64 + kk)
                    : ldg_cg4(h0 + b * 512 + (kb - 8) * 64 + kk);
                inT[(kk + 0) * 68 + b] = v.x;
                inT[(kk + 1) * 68 + b] = v.y;
                inT[(kk + 2) * 68 + b] = v.z;
                inT[(kk + 3) * 68 + b] = v.w;
            }
        }
        if (do_g0) {
            const int r = tid >> 1, kq = tid & 1;
            const float* src = W0 + (size_t)(r0 + r) * 1024 + kb * 64 + kq * 32;
#pragma unroll
            for (int i = 0; i < 8; ++i)
                *(float4*)&wlds[r * 68 + kq * 32 + i * 4] = *(const float4*)(src + i * 4);
        }
        __syncthreads();
        if (do_g0) gemm_tile(wlds, inT, z0p + (size_t)kb * 64 * G4H, r0, tid);
        if (do_hw) hw_tile(whws, inT, hwzp + (size_t)(kb - 8) * 64 * HH, rg * 32, tid);
        if (do_c1) {
            const int b = rg * 4 + kb;   // 64 distinct b
            cell_update(z1p + (size_t)b * G4H, b1, lng1, lnb1,
                        creg, c1ws + b * 512, h1 + b * 512, sred, tid);
        }
        grid_sync(gen, flags, ph++, blk);

        // ================= P2: out(t-1) + cell0(t) (+ final states) =================
        if (kb >= 4 && kb < 8) {
            const int b = rg * 4 + (kb - 4);  // 64 distinct b
            if (t >= 1) {
#pragma unroll
                for (int e = 0; e < 2; ++e) {
                    const int j = tid + e * 256;
                    float s = hwb[j];
#pragma unroll
                    for (int ks = 0; ks < 8; ++ks)
                        s += ldg_cg(hwzp + (size_t)ks * 64 * HH + b * 512 + j);
                    const float gt = 1.f / (1.f + expf(-s));
                    out[((size_t)b * TT + (t - 1)) * HH + j] =
                        gt * ldg_cg(h1 + b * 512 + j) + (1.f - gt) * ldg_cg(h0 + b * 512 + j);
                }
            }
            if (t < TT) {
                cell_update(z0p + (size_t)b * G4H, b0, lng0, lnb0,
                            creg, (float*)nullptr, h0 + b * 512, sred, tid);
            } else {
                const size_t OUT_SZ = (size_t)BB * TT * HH;
#pragma unroll
                for (int e = 0; e < 2; ++e) {
                    const int j = tid + e * 256;
                    out[OUT_SZ + b * 512 + j]                 = ldg_cg(h0 + b * 512 + j);   // h_n[0]
                    out[OUT_SZ + 32768 + b * 512 + j]         = ldg_cg(h1 + b * 512 + j);   // h_n[1]
                    out[OUT_SZ + 65536 + b * 512 + j]         = creg[e];                     // c_n[0]
                    out[OUT_SZ + 65536 + 32768 + b * 512 + j] = ldg_cg(c1ws + b * 512 + j); // c_n[1]
                }
            }
        }
        grid_sync(gen, flags, ph++, blk);
        if (t == TT) break;

        // ================= P3: gemm1(t) =================
        {
            const int b = tid >> 2, kq = tid & 3;
#pragma unroll
            for (int i = 0; i < 4; ++i) {
                const int kk = kq * 16 + i * 4;
                const float4 v = (kb < 8)
                    ? ldg_cg4(h0 + b * 512 + kb * 64 + kk)
                    : ldg_cg4(h1 + b * 512 + (kb - 8) * 64 + kk);
                inT[(kk + 0) * 68 + b] = v.x;
                inT[(kk + 1) * 68 + b] = v.y;
                inT[(kk + 2) * 68 + b] = v.z;
                inT[(kk + 3) * 68 + b] = v.w;
            }
            const int r = tid >> 1, kq2 = tid & 1;
            const float* wsrc = W1 + (size_t)(r0 + r) * 1024 + kb * 64 + kq2 * 32;
#pragma unroll
            for (int i = 0; i < 8; ++i)
                *(float4*)&wlds[r * 68 + kq2 * 32 + i * 4] = *(const float4*)(wsrc + i * 4);
            __syncthreads();
            gemm_tile(wlds, inT, z1p + (size_t)kb * 64 * G4H, r0, tid);
        }
        grid_sync(gen, flags, ph++, blk);
    }
}

extern "C" void kernel_launch(void* const* d_in, const int* in_sizes, int n_in,
                              void* d_out, int out_size, void* d_ws, size_t ws_size,
                              hipStream_t stream)
{
    (void)in_sizes; (void)n_in; (void)out_size; (void)ws_size;
    const float* x    = (const float*)d_in[0];
    const float* W0   = (const float*)d_in[1];
    const float* b0   = (const float*)d_in[2];
    const float* lng0 = (const float*)d_in[3];
    const float* lnb0 = (const float*)d_in[4];
    const float* W1   = (const float*)d_in[5];
    const float* b1   = (const float*)d_in[6];
    const float* lng1 = (const float*)d_in[7];
    const float* lnb1 = (const float*)d_in[8];
    const float* hwW  = (const float*)d_in[9];
    const float* hwb  = (const float*)d_in[10];
    float* out = (float*)d_out;
    float* ws  = (float*)d_ws;

    ln_lstm_init_kernel<<<dim3(128), dim3(256), 0, stream>>>(ws);
    LayerNormLSTMStack_55508157333865_kernel<<<dim3(NBLK), dim3(NTHR), 0, stream>>>(
        x, W0, b0, lng0, lnb0, W1, b1, lng1, lnb1, hwW, hwb, out, ws);
}

// Round 7
// 60099.463 us; speedup vs baseline: 2.4483x; 2.3665x over previous
//
#include <hip/hip_runtime.h>

#define TT 1024
#define BB 64
#define HH 512
#define DD 512
#define NBLK 256
#define NTHR 256
#define NGRP 8           // 8 batch groups x 8 rows; 32 blocks per group

// ---------------- ws layout (32-bit words), total 4,562,944 words = 18,251,776 B
#define W0T4_OFF 0               // [256 kq][2048 R][4]  transposed-packed W0
#define W1T4_OFF 2097152         // same for W1
#define H0_OFF   4194304         // [64 b][512]  h0(t) single-buffered
#define H1_OFF   4227072         // [64 b][512]
#define Z0_OFF   4259840         // [8 grp][8 bi][2048]
#define Z1_OFF   4390912         // [8 grp][8 bi][2048]
#define HWZ_OFF  4521984         // [8 grp][8 bi][512]
#define FLG_OFF  4554752         // [8 grp][32 slot][32 words]  (128B stride)

// ======== cross-block access: relaxed agent-scope atomics (MALL-coherent) ========
__device__ __forceinline__ float ldg_cg(const float* p) {
    return __hip_atomic_load(p, __ATOMIC_RELAXED, __HIP_MEMORY_SCOPE_AGENT);
}
__device__ __forceinline__ void stg_cg(float* p, float v) {
    __hip_atomic_store(p, v, __ATOMIC_RELAXED, __HIP_MEMORY_SCOPE_AGENT);
}
__device__ __forceinline__ float4 ldg_cg4(const float* p) {
    const unsigned long long* q = (const unsigned long long*)p;
    unsigned long long a = __hip_atomic_load(q,     __ATOMIC_RELAXED, __HIP_MEMORY_SCOPE_AGENT);
    unsigned long long b = __hip_atomic_load(q + 1, __ATOMIC_RELAXED, __HIP_MEMORY_SCOPE_AGENT);
    float4 v;
    ((unsigned long long*)&v)[0] = a;
    ((unsigned long long*)&v)[1] = b;
    return v;
}
__device__ __forceinline__ unsigned ldg_cgu(const unsigned* p) {
    return __hip_atomic_load(p, __ATOMIC_RELAXED, __HIP_MEMORY_SCOPE_AGENT);
}

// ======== group barrier: 32 blocks, flag-array, RELEASE-published ========
// R6 post-mortem: data stores are relaxed sc1; if vmcnt retirement does not imply
// MALL visibility, a remote block can see the flag before the data (rare, stale-value
// race -> 0.064 absmax). The RELEASE on the flag store forces all prior stores to the
// coherence point before the flag lands. Reader side needs no acquire: sc1 data loads
// read the MALL directly. Polls stay relaxed (no L2 thrash while spinning).
__device__ __forceinline__ void group_barrier(unsigned* gfl, unsigned tgt, int slot, int tid)
{
    __syncthreads();                       // join block; drains this block's vmem
    if (tid == 0)
        __hip_atomic_store(&gfl[slot * 32], tgt, __ATOMIC_RELEASE, __HIP_MEMORY_SCOPE_AGENT);
    if (tid < 32) {
        while (ldg_cgu(&gfl[tid * 32]) < tgt) __builtin_amdgcn_s_sleep(1);
    }
    __syncthreads();
}

// ---------------- init: transpose-pack weights + zero h-state + flags ----------------
__global__ void ln_lstm_init_kernel(const float* __restrict__ W0, const float* __restrict__ W1,
                                    float* __restrict__ ws)
{
    const int stride = gridDim.x * blockDim.x;
    const int idx = blockIdx.x * blockDim.x + threadIdx.x;
    // W0T4[(kq*2048 + R)*4 + c] = W0[R*1024 + kq*4 + c]
    for (int i = idx; i < 2048 * 256; i += stride) {
        const int R = i & 2047, kq = i >> 11;
        const float4 v0 = *(const float4*)&W0[(size_t)R * 1024 + kq * 4];
        const float4 v1 = *(const float4*)&W1[(size_t)R * 1024 + kq * 4];
        *(float4*)&ws[W0T4_OFF + ((size_t)kq * 2048 + R) * 4] = v0;
        *(float4*)&ws[W1T4_OFF + ((size_t)kq * 2048 + R) * 4] = v1;
    }
    for (int i = idx; i < 65536; i += stride) ws[H0_OFF + i] = 0.f;    // h0 + h1
    unsigned* uw = (unsigned*)ws;
    for (int i = idx; i < 8192; i += stride) uw[FLG_OFF + i] = 0u;     // barrier flags
}

// ---------------- full-K GEMV: 64 rows x 8 batches; K quartered across 4 waves --------
__device__ __forceinline__ void gemv_k4(const float4* __restrict__ wt, const float* __restrict__ inT,
                                        float* __restrict__ zr, int bq, int r, int Rrow,
                                        float& z0, float& z1)
{
    float a[8];
#pragma unroll
    for (int i = 0; i < 8; ++i) a[i] = 0.f;
    const float4* wp = wt + (size_t)(bq * 64) * 2048 + Rrow;
    const float* ib = inT + bq * 256;
    for (int c = 0; c < 4; ++c) {
        float4 w[16];
#pragma unroll
        for (int i = 0; i < 16; ++i) w[i] = wp[(size_t)(c * 16 + i) * 2048];
#pragma unroll
        for (int i = 0; i < 16; ++i) {
            const int kk = c * 64 + i * 4;
#pragma unroll
            for (int bi = 0; bi < 8; ++bi) {
                const float4 iv = *(const float4*)&ib[bi * 1024 + kk];   // LDS broadcast
                a[bi] += w[i].x * iv.x + w[i].y * iv.y + w[i].z * iv.z + w[i].w * iv.w;
            }
        }
    }
#pragma unroll
    for (int bi = 0; bi < 8; ++bi) zr[bq * 512 + bi * 64 + r] = a[bi];
    __syncthreads();
    z0 = 0.f; z1 = 0.f;
#pragma unroll
    for (int w2 = 0; w2 < 4; ++w2) {
        z0 += zr[w2 * 512 + bq * 64 + r];
        z1 += zr[w2 * 512 + (bq + 4) * 64 + r];
    }
}

// ---------------- block-local reductions ----------------
__device__ __forceinline__ void block_reduce8(float v[8], float* sred, int tid)
{
#pragma unroll
    for (int off = 32; off > 0; off >>= 1)
#pragma unroll
        for (int k = 0; k < 8; ++k) v[k] += __shfl_down(v[k], off, 64);
    __syncthreads();
    if ((tid & 63) == 0) {
        const int wv = tid >> 6;
#pragma unroll
        for (int k = 0; k < 8; ++k) sred[k * 4 + wv] = v[k];
    }
    __syncthreads();
#pragma unroll
    for (int k = 0; k < 8; ++k)
        v[k] = sred[k * 4 + 0] + sred[k * 4 + 1] + sred[k * 4 + 2] + sred[k * 4 + 3];
}
__device__ __forceinline__ void block_reduce2(float& s1, float& s2, float* sred, int tid)
{
#pragma unroll
    for (int off = 32; off > 0; off >>= 1) {
        s1 += __shfl_down(s1, off, 64);
        s2 += __shfl_down(s2, off, 64);
    }
    __syncthreads();
    if ((tid & 63) == 0) {
        const int wv = tid >> 6;
        sred[wv] = s1; sred[4 + wv] = s2;
    }
    __syncthreads();
    s1 = sred[0] + sred[1] + sred[2] + sred[3];
    s2 = sred[4] + sred[5] + sred[6] + sred[7];
}

// ---------------- whole LSTM cell for one batch, fully block-local ----------------
__device__ __forceinline__ void cell(const float* __restrict__ zg, const float* __restrict__ gb,
                                     const float* __restrict__ lng, const float* __restrict__ lnb,
                                     float cc[2], float* __restrict__ hws_b, float hv[2],
                                     float* sred, int tid)
{
    float z[4][2];
#pragma unroll
    for (int g = 0; g < 4; ++g) {
        z[g][0] = ldg_cg(zg + g * 512 + tid)       + gb[g * 512 + tid];
        z[g][1] = ldg_cg(zg + g * 512 + tid + 256) + gb[g * 512 + tid + 256];
    }
    float st[8];
#pragma unroll
    for (int g = 0; g < 4; ++g) {
        st[g]     = z[g][0] + z[g][1];
        st[4 + g] = z[g][0] * z[g][0] + z[g][1] * z[g][1];
    }
    block_reduce8(st, sred, tid);
    float act[4][2];
#pragma unroll
    for (int g = 0; g < 4; ++g) {
        const float mu = st[g] * (1.f / 512.f);
        const float rs = rsqrtf(st[4 + g] * (1.f / 512.f) - mu * mu + 1e-5f);
#pragma unroll
        for (int e = 0; e < 2; ++e) {
            const int j = tid + e * 256;
            const float a = (z[g][e] - mu) * rs * lng[g * 512 + j] + lnb[g * 512 + j];
            act[g][e] = (g == 2) ? tanhf(a) : 1.f / (1.f + expf(-a));
        }
    }
    float cn[2];
#pragma unroll
    for (int e = 0; e < 2; ++e) {
        cn[e] = act[1][e] * cc[e] + act[0][e] * act[2][e];   // f*c + i*g
        cc[e] = cn[e];
    }
    float s1 = cn[0] + cn[1];
    float s2 = cn[0] * cn[0] + cn[1] * cn[1];
    block_reduce2(s1, s2, sred, tid);
    const float mu = s1 * (1.f / 512.f);
    const float rs = rsqrtf(s2 * (1.f / 512.f) - mu * mu + 1e-5f);
#pragma unroll
    for (int e = 0; e < 2; ++e) {
        const int j = tid + e * 256;
        const float h = act[3][e] * tanhf((cn[e] - mu) * rs * lng[2048 + j] + lnb[2048 + j]);
        stg_cg(hws_b + j, h);
        hv[e] = h;
    }
}

__global__ __launch_bounds__(NTHR, 1)
void LayerNormLSTMStack_55508157333865_kernel(
    const float* __restrict__ x,
    const float* __restrict__ W0, const float* __restrict__ gb0,
    const float* __restrict__ lng0, const float* __restrict__ lnb0,
    const float* __restrict__ W1, const float* __restrict__ gb1,
    const float* __restrict__ lng1, const float* __restrict__ lnb1,
    const float* __restrict__ hwW, const float* __restrict__ hwb,
    float* __restrict__ out, float* __restrict__ ws)
{
    __shared__ __align__(16) float inT[8 * 1024];   // 32 KB [bi][k]
    __shared__ __align__(16) float zr[4 * 512];     // 8 KB per-wave K-partials
    __shared__ float sred[32];
    __shared__ float hwred[256];

    const int tid = threadIdx.x;
    const int grp = blockIdx.x >> 5;        // batch group (8 rows)
    const int bg  = blockIdx.x & 31;        // slot in group
    const int bb0 = grp * 8;
    const int r = tid & 63, bq = tid >> 6;
    const int R0 = bg * 64;                 // this block's 64 GEMV rows

    const float4* w0t = (const float4*)(ws + W0T4_OFF);
    const float4* w1t = (const float4*)(ws + W1T4_OFF);
    float* h0ws  = ws + H0_OFF;
    float* h1ws  = ws + H1_OFF;
    float* z0g   = ws + Z0_OFF + grp * 16384;
    float* z1g   = ws + Z1_OFF + grp * 16384;
    float* hwzg  = ws + HWZ_OFF + grp * 4096;
    unsigned* gfl = (unsigned*)ws + FLG_OFF + grp * 1024;

    float c0[2] = {0.f, 0.f}, c1[2] = {0.f, 0.f};
    unsigned ph = 0;
    const size_t OUT_SZ = (size_t)BB * TT * HH;

    for (int t = 0; t < TT; ++t) {
        const int sbi = tid >> 5, part = tid & 31;

        // ================= P1: stage [x(t)|h0(t-1)], gemv0, store z0 =================
        {
            const float* xp = x + ((size_t)(bb0 + sbi) * TT + t) * DD + part * 16;
            float* d = &inT[sbi * 1024 + part * 16];
            *(float4*)(d)      = *(const float4*)(xp);
            *(float4*)(d + 4)  = *(const float4*)(xp + 4);
            *(float4*)(d + 8)  = *(const float4*)(xp + 8);
            *(float4*)(d + 12) = *(const float4*)(xp + 12);
            const float* hp = h0ws + (size_t)(bb0 + sbi) * 512 + part * 16;   // h0(t-1): barrier-ordered
            float* dh = &inT[sbi * 1024 + 512 + part * 16];
            *(float4*)(dh)      = ldg_cg4(hp);
            *(float4*)(dh + 4)  = ldg_cg4(hp + 4);
            *(float4*)(dh + 8)  = ldg_cg4(hp + 8);
            *(float4*)(dh + 12) = ldg_cg4(hp + 12);
        }
        __syncthreads();
        {
            float z0, z1;
            gemv_k4(w0t, inT, zr, bq, r, R0 + r, z0, z1);
            stg_cg(z0g + (size_t)bq * 2048 + R0 + r, z0);
            stg_cg(z0g + (size_t)(bq + 4) * 2048 + R0 + r, z1);
        }
        group_barrier(gfl, ++ph, bg, tid);

        // ================= P2: cell0 for batch bg (blocks 0..7) =================
        if (bg < 8) {
            const int b = bb0 + bg;
            float hv0[2];
            cell(z0g + (size_t)bg * 2048, gb0, lng0, lnb0, c0, h0ws + (size_t)b * 512, hv0, sred, tid);
            if (t == TT - 1) {
#pragma unroll
                for (int e = 0; e < 2; ++e) {
                    const int j = tid + e * 256;
                    out[OUT_SZ + (size_t)b * 512 + j]         = hv0[e];   // h_n[0]
                    out[OUT_SZ + 65536 + (size_t)b * 512 + j] = c0[e];    // c_n[0]
                }
            }
        }
        group_barrier(gfl, ++ph, bg, tid);

        // ================= P3: stage [h0(t)|h1(t-1)], gemv1, highway =================
        {
            const float* hp0 = h0ws + (size_t)(bb0 + sbi) * 512 + part * 16;  // h0(t)
            float* d0 = &inT[sbi * 1024 + part * 16];
            *(float4*)(d0)      = ldg_cg4(hp0);
            *(float4*)(d0 + 4)  = ldg_cg4(hp0 + 4);
            *(float4*)(d0 + 8)  = ldg_cg4(hp0 + 8);
            *(float4*)(d0 + 12) = ldg_cg4(hp0 + 12);
            const float* hp1 = h1ws + (size_t)(bb0 + sbi) * 512 + part * 16;  // h1(t-1)
            float* dh = &inT[sbi * 1024 + 512 + part * 16];
            *(float4*)(dh)      = ldg_cg4(hp1);
            *(float4*)(dh + 4)  = ldg_cg4(hp1 + 4);
            *(float4*)(dh + 8)  = ldg_cg4(hp1 + 8);
            *(float4*)(dh + 12) = ldg_cg4(hp1 + 12);
        }
        __syncthreads();
        {
            float z0, z1;
            gemv_k4(w1t, inT, zr, bq, r, R0 + r, z0, z1);
            stg_cg(z1g + (size_t)bq * 2048 + R0 + r, z0);
            stg_cg(z1g + (size_t)(bq + 4) * 2048 + R0 + r, z1);
        }
        // highway rows [bg*16, +16) x 8 batches; 256 threads = 2 K-halves per output
        {
            const int rh = tid & 15, bi = (tid >> 4) & 7, hf = tid >> 7;
            const float* wr = hwW + (size_t)(bg * 16 + rh) * 512 + hf * 256;
            const float* ibh = &inT[bi * 1024 + hf * 256];      // h0(t) half
            float acc = 0.f;
#pragma unroll 8
            for (int k = 0; k < 256; k += 4) {
                const float4 wv = *(const float4*)&wr[k];
                const float4 iv = *(const float4*)&ibh[k];
                acc += wv.x * iv.x + wv.y * iv.y + wv.z * iv.z + wv.w * iv.w;
            }
            hwred[tid] = acc;
            __syncthreads();
            if (tid < 128)
                stg_cg(hwzg + (size_t)bi * 512 + bg * 16 + rh, hwred[tid] + hwred[tid + 128]);
        }
        group_barrier(gfl, ++ph, bg, tid);

        // ================= P4: cell1 + out(t) for batch bg (blocks 0..7) =================
        if (bg < 8) {
            const int b = bb0 + bg;
            float hv1[2];
            cell(z1g + (size_t)bg * 2048, gb1, lng1, lnb1, c1, h1ws + (size_t)b * 512, hv1, sred, tid);
#pragma unroll
            for (int e = 0; e < 2; ++e) {
                const int j = tid + e * 256;
                const float hz = ldg_cg(hwzg + (size_t)bg * 512 + j) + hwb[j];
                const float gt = 1.f / (1.f + expf(-hz));
                const float h0v = ldg_cg(h0ws + (size_t)b * 512 + j);
                out[((size_t)b * TT + t) * HH + j] = gt * hv1[e] + (1.f - gt) * h0v;
            }
            if (t == TT - 1) {
#pragma unroll
                for (int e = 0; e < 2; ++e) {
                    const int j = tid + e * 256;
                    out[OUT_SZ + 32768 + (size_t)b * 512 + j] = hv1[e];   // h_n[1]
                    out[OUT_SZ + 98304 + (size_t)b * 512 + j] = c1[e];    // c_n[1]
                }
            }
        }
        // 4th barrier: closes ALL remaining cross-step edges (belt & braces; removes
        // the "no-trailing-barrier" reasoning as a correctness dependency).
        group_barrier(gfl, ++ph, bg, tid);
    } // t
}

extern "C" void kernel_launch(void* const* d_in, const int* in_sizes, int n_in,
                              void* d_out, int out_size, void* d_ws, size_t ws_size,
                              hipStream_t stream)
{
    (void)in_sizes; (void)n_in; (void)out_size; (void)ws_size;
    const float* x    = (const float*)d_in[0];
    const float* W0   = (const float*)d_in[1];
    const float* b0   = (const float*)d_in[2];
    const float* lng0 = (const float*)d_in[3];
    const float* lnb0 = (const float*)d_in[4];
    const float* W1   = (const float*)d_in[5];
    const float* b1   = (const float*)d_in[6];
    const float* lng1 = (const float*)d_in[7];
    const float* lnb1 = (const float*)d_in[8];
    const float* hwW  = (const float*)d_in[9];
    const float* hwb  = (const float*)d_in[10];
    float* out = (float*)d_out;
    float* ws  = (float*)d_ws;

    ln_lstm_init_kernel<<<dim3(256), dim3(256), 0, stream>>>(W0, W1, ws);
    LayerNormLSTMStack_55508157333865_kernel<<<dim3(NBLK), dim3(NTHR), 0, stream>>>(
        x, W0, b0, lng0, lnb0, W1, b1, lng1, lnb1, hwW, hwb, out, ws);
}

// Round 8
// 51918.530 us; speedup vs baseline: 2.8341x; 1.1576x over previous
//
#include <hip/hip_runtime.h>

#define TT 1024
#define BB 64
#define HH 512
#define DD 512
#define NBLK 256
#define NTHR 256
#define NGRP 8           // 8 batch groups x 8 rows; 32 blocks per group

// ---------------- ws layout (32-bit words), total 4,562,944 words = 18,251,776 B (== R7, proven)
#define W0T4_OFF 0               // [256 kq][2048 R][4]  transposed-packed W0
#define W1T4_OFF 2097152         // same for W1
#define H0_OFF   4194304         // [64 b][512]  h0 single-buffered
#define H1_OFF   4227072         // [64 b][512]
#define Z0_OFF   4259840         // [8 grp][8 bi][2048]
#define Z1_OFF   4390912         // [8 grp][8 bi][2048]
#define HWZ_OFF  4521984         // [8 grp][8 bi][512]
#define FLG_OFF  4554752         // [8 grp][32 slot][32 words]  (128B stride)

// ======== cross-block access: relaxed agent-scope atomics (MALL-coherent) ========
__device__ __forceinline__ float ldg_cg(const float* p) {
    return __hip_atomic_load(p, __ATOMIC_RELAXED, __HIP_MEMORY_SCOPE_AGENT);
}
__device__ __forceinline__ void stg_cg(float* p, float v) {
    __hip_atomic_store(p, v, __ATOMIC_RELAXED, __HIP_MEMORY_SCOPE_AGENT);
}
__device__ __forceinline__ float4 ldg_cg4(const float* p) {
    const unsigned long long* q = (const unsigned long long*)p;
    unsigned long long a = __hip_atomic_load(q,     __ATOMIC_RELAXED, __HIP_MEMORY_SCOPE_AGENT);
    unsigned long long b = __hip_atomic_load(q + 1, __ATOMIC_RELAXED, __HIP_MEMORY_SCOPE_AGENT);
    float4 v;
    ((unsigned long long*)&v)[0] = a;
    ((unsigned long long*)&v)[1] = b;
    return v;
}
__device__ __forceinline__ unsigned ldg_cgu(const unsigned* p) {
    return __hip_atomic_load(p, __ATOMIC_RELAXED, __HIP_MEMORY_SCOPE_AGENT);
}

// ======== group barrier: 32 blocks, flag-array, RELEASE-published (R7-proven) ========
// RELEASE on the flag store forces all prior stores to the coherence point (MALL)
// before the flag lands (vmcnt drain + L2 writeback). Readers poll relaxed; sc1 data
// loads read the MALL directly, so no reader-side acquire needed.
__device__ __forceinline__ void group_barrier(unsigned* gfl, unsigned tgt, int slot, int tid)
{
    __syncthreads();
    if (tid == 0)
        __hip_atomic_store(&gfl[slot * 32], tgt, __ATOMIC_RELEASE, __HIP_MEMORY_SCOPE_AGENT);
    if (tid < 32) {
        while (ldg_cgu(&gfl[tid * 32]) < tgt) __builtin_amdgcn_s_sleep(1);
    }
    __syncthreads();
}

// ---------------- init: transpose-pack weights + zero h-state + flags ----------------
__global__ void ln_lstm_init_kernel(const float* __restrict__ W0, const float* __restrict__ W1,
                                    float* __restrict__ ws)
{
    const int stride = gridDim.x * blockDim.x;
    const int idx = blockIdx.x * blockDim.x + threadIdx.x;
    for (int i = idx; i < 2048 * 256; i += stride) {
        const int R = i & 2047, kq = i >> 11;
        const float4 v0 = *(const float4*)&W0[(size_t)R * 1024 + kq * 4];
        const float4 v1 = *(const float4*)&W1[(size_t)R * 1024 + kq * 4];
        *(float4*)&ws[W0T4_OFF + ((size_t)kq * 2048 + R) * 4] = v0;
        *(float4*)&ws[W1T4_OFF + ((size_t)kq * 2048 + R) * 4] = v1;
    }
    for (int i = idx; i < 65536; i += stride) ws[H0_OFF + i] = 0.f;    // h0 + h1
    unsigned* uw = (unsigned*)ws;
    for (int i = idx; i < 8192; i += stride) uw[FLG_OFF + i] = 0u;     // barrier flags
}

// ---------------- full-K GEMV: 64 rows x 8 batches; K quartered across 4 waves --------
__device__ __forceinline__ void gemv_k4(const float4* __restrict__ wt, const float* __restrict__ inT,
                                        float* __restrict__ zr, int bq, int r, int Rrow,
                                        float& z0, float& z1)
{
    float a[8];
#pragma unroll
    for (int i = 0; i < 8; ++i) a[i] = 0.f;
    const float4* wp = wt + (size_t)(bq * 64) * 2048 + Rrow;
    const float* ib = inT + bq * 256;
    for (int c = 0; c < 4; ++c) {
        float4 w[16];
#pragma unroll
        for (int i = 0; i < 16; ++i) w[i] = wp[(size_t)(c * 16 + i) * 2048];
#pragma unroll
        for (int i = 0; i < 16; ++i) {
            const int kk = c * 64 + i * 4;
#pragma unroll
            for (int bi = 0; bi < 8; ++bi) {
                const float4 iv = *(const float4*)&ib[bi * 1024 + kk];   // LDS broadcast
                a[bi] += w[i].x * iv.x + w[i].y * iv.y + w[i].z * iv.z + w[i].w * iv.w;
            }
        }
    }
#pragma unroll
    for (int bi = 0; bi < 8; ++bi) zr[bq * 512 + bi * 64 + r] = a[bi];
    __syncthreads();
    z0 = 0.f; z1 = 0.f;
#pragma unroll
    for (int w2 = 0; w2 < 4; ++w2) {
        z0 += zr[w2 * 512 + bq * 64 + r];
        z1 += zr[w2 * 512 + (bq + 4) * 64 + r];
    }
}

// ---------------- block-local reductions ----------------
__device__ __forceinline__ void block_reduce8(float v[8], float* sred, int tid)
{
#pragma unroll
    for (int off = 32; off > 0; off >>= 1)
#pragma unroll
        for (int k = 0; k < 8; ++k) v[k] += __shfl_down(v[k], off, 64);
    __syncthreads();
    if ((tid & 63) == 0) {
        const int wv = tid >> 6;
#pragma unroll
        for (int k = 0; k < 8; ++k) sred[k * 4 + wv] = v[k];
    }
    __syncthreads();
#pragma unroll
    for (int k = 0; k < 8; ++k)
        v[k] = sred[k * 4 + 0] + sred[k * 4 + 1] + sred[k * 4 + 2] + sred[k * 4 + 3];
}
__device__ __forceinline__ void block_reduce2(float& s1, float& s2, float* sred, int tid)
{
#pragma unroll
    for (int off = 32; off > 0; off >>= 1) {
        s1 += __shfl_down(s1, off, 64);
        s2 += __shfl_down(s2, off, 64);
    }
    __syncthreads();
    if ((tid & 63) == 0) {
        const int wv = tid >> 6;
        sred[wv] = s1; sred[4 + wv] = s2;
    }
    __syncthreads();
    s1 = sred[0] + sred[1] + sred[2] + sred[3];
    s2 = sred[4] + sred[5] + sred[6] + sred[7];
}

// ---------------- whole LSTM cell for one batch, fully block-local ----------------
__device__ __forceinline__ void cell(const float* __restrict__ zg, const float* __restrict__ gb,
                                     const float* __restrict__ lng, const float* __restrict__ lnb,
                                     float cc[2], float* __restrict__ hws_b, float hv[2],
                                     float* sred, int tid)
{
    float z[4][2];
#pragma unroll
    for (int g = 0; g < 4; ++g) {
        z[g][0] = ldg_cg(zg + g * 512 + tid)       + gb[g * 512 + tid];
        z[g][1] = ldg_cg(zg + g * 512 + tid + 256) + gb[g * 512 + tid + 256];
    }
    float st[8];
#pragma unroll
    for (int g = 0; g < 4; ++g) {
        st[g]     = z[g][0] + z[g][1];
        st[4 + g] = z[g][0] * z[g][0] + z[g][1] * z[g][1];
    }
    block_reduce8(st, sred, tid);
    float act[4][2];
#pragma unroll
    for (int g = 0; g < 4; ++g) {
        const float mu = st[g] * (1.f / 512.f);
        const float rs = rsqrtf(st[4 + g] * (1.f / 512.f) - mu * mu + 1e-5f);
#pragma unroll
        for (int e = 0; e < 2; ++e) {
            const int j = tid + e * 256;
            const float a = (z[g][e] - mu) * rs * lng[g * 512 + j] + lnb[g * 512 + j];
            act[g][e] = (g == 2) ? tanhf(a) : 1.f / (1.f + expf(-a));
        }
    }
    float cn[2];
#pragma unroll
    for (int e = 0; e < 2; ++e) {
        cn[e] = act[1][e] * cc[e] + act[0][e] * act[2][e];   // f*c + i*g
        cc[e] = cn[e];
    }
    float s1 = cn[0] + cn[1];
    float s2 = cn[0] * cn[0] + cn[1] * cn[1];
    block_reduce2(s1, s2, sred, tid);
    const float mu = s1 * (1.f / 512.f);
    const float rs = rsqrtf(s2 * (1.f / 512.f) - mu * mu + 1e-5f);
#pragma unroll
    for (int e = 0; e < 2; ++e) {
        const int j = tid + e * 256;
        const float h = act[3][e] * tanhf((cn[e] - mu) * rs * lng[2048 + j] + lnb[2048 + j]);
        stg_cg(hws_b + j, h);
        hv[e] = h;
    }
}

__global__ __launch_bounds__(NTHR, 1)
void LayerNormLSTMStack_55508157333865_kernel(
    const float* __restrict__ x,
    const float* __restrict__ W0, const float* __restrict__ gb0,
    const float* __restrict__ lng0, const float* __restrict__ lnb0,
    const float* __restrict__ W1, const float* __restrict__ gb1,
    const float* __restrict__ lng1, const float* __restrict__ lnb1,
    const float* __restrict__ hwW, const float* __restrict__ hwb,
    float* __restrict__ out, float* __restrict__ ws)
{
    __shared__ __align__(16) float inT[8 * 1024];   // 32 KB [bi][k]
    __shared__ __align__(16) float zr[4 * 512];     // 8 KB per-wave K-partials
    __shared__ float sred[32];
    __shared__ float hwred[256];

    const int tid = threadIdx.x;
    const int grp = blockIdx.x >> 5;        // batch group (8 rows)
    const int bg  = blockIdx.x & 31;        // slot in group
    const int bb0 = grp * 8;
    const int r = tid & 63, bq = tid >> 6;
    const int R0 = bg * 64;                 // this block's 64 GEMV rows

    const float4* w0t = (const float4*)(ws + W0T4_OFF);
    const float4* w1t = (const float4*)(ws + W1T4_OFF);
    float* h0ws  = ws + H0_OFF;
    float* h1ws  = ws + H1_OFF;
    float* z0g   = ws + Z0_OFF + grp * 16384;
    float* z1g   = ws + Z1_OFF + grp * 16384;
    float* hwzg  = ws + HWZ_OFF + grp * 4096;
    unsigned* gfl = (unsigned*)ws + FLG_OFF + grp * 1024;

    float c0[2] = {0.f, 0.f}, c1[2] = {0.f, 0.f};
    float hv0[2] = {0.f, 0.f};              // h0(t) for this block's batch (bg<8), kept in regs
    unsigned ph = 0;
    const size_t OUT_SZ = (size_t)BB * TT * HH;
    const int sbi = tid >> 5, part = tid & 31;
    const float hwb0 = hwb[tid], hwb1 = hwb[tid + 256];

    // ================= prologue: gemv0(0) ; cell0(0) =================
    {
        const float* xp = x + ((size_t)(bb0 + sbi) * TT + 0) * DD + part * 16;
        float* d = &inT[sbi * 1024 + part * 16];
        *(float4*)(d)      = *(const float4*)(xp);
        *(float4*)(d + 4)  = *(const float4*)(xp + 4);
        *(float4*)(d + 8)  = *(const float4*)(xp + 8);
        *(float4*)(d + 12) = *(const float4*)(xp + 12);
        float* dh = &inT[sbi * 1024 + 512 + part * 16];   // h0(-1) = 0
        *(float4*)(dh) = make_float4(0.f, 0.f, 0.f, 0.f);
        *(float4*)(dh + 4) = make_float4(0.f, 0.f, 0.f, 0.f);
        *(float4*)(dh + 8) = make_float4(0.f, 0.f, 0.f, 0.f);
        *(float4*)(dh + 12) = make_float4(0.f, 0.f, 0.f, 0.f);
    }
    __syncthreads();
    {
        float z0, z1;
        gemv_k4(w0t, inT, zr, bq, r, R0 + r, z0, z1);
        stg_cg(z0g + (size_t)bq * 2048 + R0 + r, z0);
        stg_cg(z0g + (size_t)(bq + 4) * 2048 + R0 + r, z1);
    }
    group_barrier(gfl, ++ph, bg, tid);
    if (bg < 8)
        cell(z0g + (size_t)bg * 2048, gb0, lng0, lnb0, c0, h0ws + (size_t)(bb0 + bg) * 512, hv0, sred, tid);
    group_barrier(gfl, ++ph, bg, tid);

    for (int t = 0; t < TT; ++t) {
        const bool more = (t + 1 < TT);

        // ================= P_A: gemv1(t) + hw(t) + gemv0(t+1) =================
        // stage inT = [h0(t) | h1(t-1)]
        {
            const float* hp0 = h0ws + (size_t)(bb0 + sbi) * 512 + part * 16;
            float* d0 = &inT[sbi * 1024 + part * 16];
            *(float4*)(d0)      = ldg_cg4(hp0);
            *(float4*)(d0 + 4)  = ldg_cg4(hp0 + 4);
            *(float4*)(d0 + 8)  = ldg_cg4(hp0 + 8);
            *(float4*)(d0 + 12) = ldg_cg4(hp0 + 12);
            const float* hp1 = h1ws + (size_t)(bb0 + sbi) * 512 + part * 16;
            float* dh = &inT[sbi * 1024 + 512 + part * 16];
            *(float4*)(dh)      = ldg_cg4(hp1);
            *(float4*)(dh + 4)  = ldg_cg4(hp1 + 4);
            *(float4*)(dh + 8)  = ldg_cg4(hp1 + 8);
            *(float4*)(dh + 12) = ldg_cg4(hp1 + 12);
        }
        __syncthreads();
        {
            float z0, z1;
            gemv_k4(w1t, inT, zr, bq, r, R0 + r, z0, z1);
            stg_cg(z1g + (size_t)bq * 2048 + R0 + r, z0);
            stg_cg(z1g + (size_t)(bq + 4) * 2048 + R0 + r, z1);
        }
        // highway rows [bg*16, +16) x 8 batches (inT first half = h0(t))
        {
            const int rh = tid & 15, bi = (tid >> 4) & 7, hf = tid >> 7;
            const float* wr = hwW + (size_t)(bg * 16 + rh) * 512 + hf * 256;
            const float* ibh = &inT[bi * 1024 + hf * 256];
            float acc = 0.f;
#pragma unroll 8
            for (int k = 0; k < 256; k += 4) {
                const float4 wv = *(const float4*)&wr[k];
                const float4 iv = *(const float4*)&ibh[k];
                acc += wv.x * iv.x + wv.y * iv.y + wv.z * iv.z + wv.w * iv.w;
            }
            hwred[tid] = acc;
            __syncthreads();
            if (tid < 128)
                stg_cg(hwzg + (size_t)bi * 512 + bg * 16 + rh, hwred[tid] + hwred[tid + 128]);
        }
        if (more) {
            // restage inT = [x(t+1) | h0(t)]: h0 moved LDS->LDS, x from global
            float4 h0a, h0b, h0c, h0d;
            {
                const float* src = &inT[sbi * 1024 + part * 16];   // h0(t) currently in first half
                h0a = *(const float4*)(src);
                h0b = *(const float4*)(src + 4);
                h0c = *(const float4*)(src + 8);
                h0d = *(const float4*)(src + 12);
            }
            const float* xp = x + ((size_t)(bb0 + sbi) * TT + (t + 1)) * DD + part * 16;
            const float4 xa = *(const float4*)(xp);
            const float4 xb = *(const float4*)(xp + 4);
            const float4 xc = *(const float4*)(xp + 8);
            const float4 xd = *(const float4*)(xp + 12);
            __syncthreads();                 // all reads of inT (gemv1/hw/h0-copy) done
            {
                float* dh = &inT[sbi * 1024 + 512 + part * 16];
                *(float4*)(dh)      = h0a;
                *(float4*)(dh + 4)  = h0b;
                *(float4*)(dh + 8)  = h0c;
                *(float4*)(dh + 12) = h0d;
                float* d0 = &inT[sbi * 1024 + part * 16];
                *(float4*)(d0)      = xa;
                *(float4*)(d0 + 4)  = xb;
                *(float4*)(d0 + 8)  = xc;
                *(float4*)(d0 + 12) = xd;
            }
            __syncthreads();
            float z0, z1;
            gemv_k4(w0t, inT, zr, bq, r, R0 + r, z0, z1);
            stg_cg(z0g + (size_t)bq * 2048 + R0 + r, z0);
            stg_cg(z0g + (size_t)(bq + 4) * 2048 + R0 + r, z1);
        }
        group_barrier(gfl, ++ph, bg, tid);

        // ================= P_B: cell1(t) + out(t) + cell0(t+1) =================
        if (bg < 8) {
            const int b = bb0 + bg;
            float hv1[2];
            cell(z1g + (size_t)bg * 2048, gb1, lng1, lnb1, c1, h1ws + (size_t)b * 512, hv1, sred, tid);
            {
                const float hz0 = ldg_cg(hwzg + (size_t)bg * 512 + tid) + hwb0;
                const float hz1 = ldg_cg(hwzg + (size_t)bg * 512 + tid + 256) + hwb1;
                const float gt0 = 1.f / (1.f + expf(-hz0));
                const float gt1 = 1.f / (1.f + expf(-hz1));
                out[((size_t)b * TT + t) * HH + tid]       = gt0 * hv1[0] + (1.f - gt0) * hv0[0];
                out[((size_t)b * TT + t) * HH + tid + 256] = gt1 * hv1[1] + (1.f - gt1) * hv0[1];
            }
            if (more) {
                cell(z0g + (size_t)bg * 2048, gb0, lng0, lnb0, c0, h0ws + (size_t)b * 512, hv0, sred, tid);
            } else {
                // final states: h0(TT-1)=hv0/c0 (regs), h1(TT-1)=hv1/c1
#pragma unroll
                for (int e = 0; e < 2; ++e) {
                    const int j = tid + e * 256;
                    out[OUT_SZ + (size_t)b * 512 + j]          = hv0[e];  // h_n[0]
                    out[OUT_SZ + 32768 + (size_t)b * 512 + j]  = hv1[e];  // h_n[1]
                    out[OUT_SZ + 65536 + (size_t)b * 512 + j]  = c0[e];   // c_n[0]
                    out[OUT_SZ + 98304 + (size_t)b * 512 + j]  = c1[e];   // c_n[1]
                }
            }
        }
        group_barrier(gfl, ++ph, bg, tid);
    } // t
}

extern "C" void kernel_launch(void* const* d_in, const int* in_sizes, int n_in,
                              void* d_out, int out_size, void* d_ws, size_t ws_size,
                              hipStream_t stream)
{
    (void)in_sizes; (void)n_in; (void)out_size; (void)ws_size;
    const float* x    = (const float*)d_in[0];
    const float* W0   = (const float*)d_in[1];
    const float* b0   = (const float*)d_in[2];
    const float* lng0 = (const float*)d_in[3];
    const float* lnb0 = (const float*)d_in[4];
    const float* W1   = (const float*)d_in[5];
    const float* b1   = (const float*)d_in[6];
    const float* lng1 = (const float*)d_in[7];
    const float* lnb1 = (const float*)d_in[8];
    const float* hwW  = (const float*)d_in[9];
    const float* hwb  = (const float*)d_in[10];
    float* out = (float*)d_out;
    float* ws  = (float*)d_ws;

    ln_lstm_init_kernel<<<dim3(256), dim3(256), 0, stream>>>(W0, W1, ws);
    LayerNormLSTMStack_55508157333865_kernel<<<dim3(NBLK), dim3(NTHR), 0, stream>>>(
        x, W0, b0, lng0, lnb0, W1, b1, lng1, lnb1, hwW, hwb, out, ws);
}